// Round 7
// baseline (452.037 us; speedup 1.0000x reference)
//
#include <hip/hip_runtime.h>
#include <hip/hip_bf16.h>

// Problem constants: B=2, S=2048, HID=2048, H=16, HD=128, HD2=64, LAT=256
#define BB 2
#define SS 2048
#define HID 2048
#define NH 16
#define BS (BB*SS)          // 4096 rows
#define SCALE_L2E 0.12751744502911988f  // (1/sqrt(128)) * log2(e)

typedef __bf16 bf16x8 __attribute__((ext_vector_type(8)));
typedef float f32x4 __attribute__((ext_vector_type(4)));

__device__ __forceinline__ bf16x8 ld_frag(const __hip_bfloat16* p) {
    uint4 u = *reinterpret_cast<const uint4*>(p);
    return __builtin_bit_cast(bf16x8, u);
}
__device__ __forceinline__ void store_c(__hip_bfloat16* C, size_t idx, float v) {
    C[idx] = __float2bfloat16(v);
}
__device__ __forceinline__ void store_c(float* C, size_t idx, float v) {
    C[idx] = v;
}
__device__ __forceinline__ ushort bf_bits(float v) {
    __hip_bfloat16 h = __float2bfloat16(v);
    return *reinterpret_cast<ushort*>(&h);
}
__device__ __forceinline__ uint pack_bf2(float a, float b) {
    __hip_bfloat162 h2 = __float22bfloat162_rn(float2{a, b});
    return *reinterpret_cast<uint*>(&h2);
}

// async global->LDS, 16B per lane; lds addr must be wave-uniform base + lane*16
#define GLD16(gp, lp) \
  __builtin_amdgcn_global_load_lds((const __attribute__((address_space(1))) void*)(gp), \
                                   (__attribute__((address_space(3))) void*)(lp), 16, 0, 0)

// ---------------------------------------------------------------------------
// fp32 -> bf16 flat convert (hs)
// ---------------------------------------------------------------------------
__global__ __launch_bounds__(256) void convert_kernel(
    const float* __restrict__ src, __hip_bfloat16* __restrict__ dst, int n8)
{
    int i = blockIdx.x * blockDim.x + threadIdx.x;
    if (i >= n8) return;
    float4 a = reinterpret_cast<const float4*>(src)[2 * i];
    float4 b = reinterpret_cast<const float4*>(src)[2 * i + 1];
    ushort u[8] = { bf_bits(a.x), bf_bits(a.y), bf_bits(a.z), bf_bits(a.w),
                    bf_bits(b.x), bf_bits(b.y), bf_bits(b.z), bf_bits(b.w) };
    reinterpret_cast<uint4*>(dst)[i] = *reinterpret_cast<uint4*>(u);
}

// ---------------------------------------------------------------------------
// Fused weight transpose+convert: 8 segments, src fp32 [R][C] -> dst bf16 [C][R]
// ---------------------------------------------------------------------------
__global__ __launch_bounds__(256) void transpose_weights_kernel(
    const float* s0, const float* s1, const float* s2, const float* s3,
    const float* s4, const float* s5, const float* s6, const float* s7,
    __hip_bfloat16* WT1, __hip_bfloat16* WT2, __hip_bfloat16* WT3,
    __hip_bfloat16* WTo)
{
    const float* srcs[8] = { s0, s1, s2, s3, s4, s5, s6, s7 };
    const int Rs[8] = { 2048, 2048, 2048, 256, 256, 256, 256, 2048 };
    const int Cs[8] = { 256, 256, 1024, 1024, 2048, 1024, 1024, 2048 };
    __hip_bfloat16* dsts[8] = {
        WT1, WT1 + (size_t)256 * 2048, WT1 + (size_t)512 * 2048,
        WT2, WT2 + (size_t)1024 * 256,
        WT3, WT3 + (size_t)1024 * 256,
        WTo };
    const int prefix[9] = { 0, 512, 1024, 3072, 3328, 3840, 4096, 4352, 8448 };

    int bid = blockIdx.x;
    int seg = 0;
    #pragma unroll
    for (int i = 0; i < 8; i++) if (bid >= prefix[i + 1]) seg = i + 1;
    int local = bid - prefix[seg];
    int R = Rs[seg], C = Cs[seg];
    int tilesC = C / 32;
    int tr = local / tilesC, tc = local % tilesC;
    int r0 = tr * 32, c0 = tc * 32;
    const float* src = srcs[seg];
    __hip_bfloat16* dst = dsts[seg];

    __shared__ float Ts[32][33];
    int t = threadIdx.x;
    int ty = t >> 5, tx = t & 31;
    #pragma unroll
    for (int k = 0; k < 4; k++) {
        int r = ty + k * 8;
        Ts[r][tx] = src[(size_t)(r0 + r) * C + c0 + tx];
    }
    __syncthreads();
    #pragma unroll
    for (int k = 0; k < 4; k++) {
        int r = ty + k * 8;
        dst[(size_t)(c0 + r) * R + r0 + tx] = __float2bfloat16(Ts[tx][r]);
    }
}

// ---------------------------------------------------------------------------
// m97-style GEMM: C = A[M,K] * Bt[N,K]^T, bf16 in, fp32 acc.
// 128x128 tile, BK=32, global_load_lds staging, 4 waves each 64x64.
// Epilogue routing: col < splitN -> (C0,...) else (C1,...). cm = output scale.
//   s64==0: plain col;  s64==1: col c -> (c>>6)*128 + (c&63) + off (head scatter)
//   s64==2: transposed store: Cp[(size_t)c*4096 + row]  (V-transpose for flash)
// ---------------------------------------------------------------------------
template <typename TC>
__global__ __launch_bounds__(256) void gemm_bt_kernel(
    const __hip_bfloat16* __restrict__ A, int lda,
    const __hip_bfloat16* __restrict__ Bt,
    TC* __restrict__ C0, int ldc0, int sp0, int off0, float cm0,
    TC* __restrict__ C1, int ldc1, int sp1, int off1, float cm1,
    int splitN, int K)
{
    __shared__ alignas(16) __hip_bfloat16 As[128 * 32];
    __shared__ alignas(16) __hip_bfloat16 Bs[128 * 32];

    const int bn = blockIdx.x * 128;
    const int bm = blockIdx.y * 128;
    const int t = threadIdx.x;
    const int w = t >> 6;
    const int lane = t & 63;
    const int l15 = lane & 15;
    const int quad = lane >> 4;
    const int wm = (w & 1) * 64;
    const int wn = (w >> 1) * 64;

    const int srow = lane >> 2;          // 0..15
    const int skcol = (lane & 3) * 8;    // 0,8,16,24

    f32x4 acc[4][4] = {};

    for (int k0 = 0; k0 < K; k0 += 32) {
        __syncthreads();
        #pragma unroll
        for (int i = 0; i < 2; i++) {
            int r = w * 32 + i * 16 + srow;
            GLD16(A + (size_t)(bm + r) * lda + k0 + skcol, &As[r * 32 + skcol]);
            GLD16(Bt + (size_t)(bn + r) * K + k0 + skcol, &Bs[r * 32 + skcol]);
        }
        __syncthreads();

        bf16x8 af[4], bf[4];
        #pragma unroll
        for (int mt = 0; mt < 4; mt++)
            af[mt] = ld_frag(&As[(wm + mt * 16 + l15) * 32 + quad * 8]);
        #pragma unroll
        for (int nt = 0; nt < 4; nt++)
            bf[nt] = ld_frag(&Bs[(wn + nt * 16 + l15) * 32 + quad * 8]);
        #pragma unroll
        for (int mt = 0; mt < 4; mt++)
            #pragma unroll
            for (int nt = 0; nt < 4; nt++)
                acc[mt][nt] = __builtin_amdgcn_mfma_f32_16x16x32_bf16(
                    af[mt], bf[nt], acc[mt][nt], 0, 0, 0);
    }

    #pragma unroll
    for (int nt = 0; nt < 4; nt++) {
        int col = bn + wn + nt * 16 + l15;
        TC* Cp; int c, ld, s64, off; float cm;
        if (col < splitN) { Cp = C0; c = col; ld = ldc0; s64 = sp0; off = off0; cm = cm0; }
        else { Cp = C1; c = col - splitN; ld = ldc1; s64 = sp1; off = off1; cm = cm1; }
        if (s64 == 2) {
            #pragma unroll
            for (int mt = 0; mt < 4; mt++) {
                int row0 = bm + wm + mt * 16 + quad * 4;
                #pragma unroll
                for (int r = 0; r < 4; r++)
                    store_c(Cp, (size_t)c * 4096 + row0 + r, acc[mt][nt][r] * cm);
            }
        } else {
            int oc = s64 ? ((c >> 6) * 128 + (c & 63) + off) : c;
            #pragma unroll
            for (int mt = 0; mt < 4; mt++) {
                #pragma unroll
                for (int r = 0; r < 4; r++) {
                    int row = bm + wm + mt * 16 + quad * 4 + r;
                    store_c(Cp, (size_t)row * ld + oc, acc[mt][nt][r] * cm);
                }
            }
        }
    }
}

// ---------------------------------------------------------------------------
// RoPE in-place on K/Q rope halves: cols h*128+64+i and h*128+96+i rotated.
// (Rotation is linear, so the SCALE_L2E pre-scale of Q is preserved.)
// ---------------------------------------------------------------------------
__global__ __launch_bounds__(256) void rope_kernel(
    __hip_bfloat16* __restrict__ Kb, __hip_bfloat16* __restrict__ Qb)
{
    int idx = blockIdx.x * blockDim.x + threadIdx.x;
    if (idx >= BS * NH * 32) return;
    int i = idx & 31;
    int h = (idx >> 5) & 15;
    int row = idx >> 9;
    int s = row & (SS - 1);

    float inv = exp2f(-(float)i * 0.4152410118609203f);  // 10000^(-i/32)
    float ang = (float)s * inv;
    float sn = sinf(ang), cs = cosf(ang);

    size_t obase = (size_t)row * 2048 + h * 128 + 64 + i;
    {
        float x1 = __bfloat162float(Kb[obase]);
        float x2 = __bfloat162float(Kb[obase + 32]);
        Kb[obase]      = __float2bfloat16(x1 * cs - x2 * sn);
        Kb[obase + 32] = __float2bfloat16(x1 * sn + x2 * cs);
    }
    {
        float x1 = __bfloat162float(Qb[obase]);
        float x2 = __bfloat162float(Qb[obase + 32]);
        Qb[obase]      = __float2bfloat16(x1 * cs - x2 * sn);
        Qb[obase + 32] = __float2bfloat16(x1 * sn + x2 * cs);
    }
}

// ---------------------------------------------------------------------------
// Flash attention v6. Block = 256 thr (4 waves), q-tile 128 (32 q/wave),
// kv-tile 64, K/Vt staged via global_load_lds. Big-first dispatch (LPT greedy
// under the dynamic scheduler — r6's static pairing regressed). Conflict-free
// LDS chunk swizzle: store chunk (lane&3)^((lane>>3)&3), read slot
// quad^((l15>>1)&3) -> every aligned 8-lane phase covers all 8 bank groups.
// Q pre-scaled by SCALE*log2e (folded into G3); softmax in base-2;
// alpha-rescale skipped when no lane's running max changed.
// ---------------------------------------------------------------------------
__global__ __launch_bounds__(256) void flash_attn_kernel(
    const __hip_bfloat16* __restrict__ Q,
    const __hip_bfloat16* __restrict__ Kb,
    const __hip_bfloat16* __restrict__ Vt,
    __hip_bfloat16* __restrict__ O)
{
    __shared__ alignas(16) __hip_bfloat16 Kt[4 * 64 * 32];   // subtile ds: [64 kv][32 d]
    __shared__ alignas(16) __hip_bfloat16 Vs[2 * 128 * 32];  // subtile kvh: [128 d][32 kv]
    __shared__ alignas(16) __hip_bfloat16 Sp[4][32 * 72];    // per-wave P [32 q][72]

    const int bxq = (gridDim.x - 1) - blockIdx.x;   // big blocks dispatched first
    const int h = blockIdx.y;
    const int b = blockIdx.z;
    const int t = threadIdx.x;
    const int w = t >> 6;
    const int lane = t & 63;
    const int l15 = lane & 15;
    const int quad = lane >> 4;
    const int qbase = bxq * 128;
    const int qmin_w = qbase + w * 32;      // min q row of this wave
    const int qmax_w = qmin_w + 31;         // max q row of this wave

    const __hip_bfloat16* Kbase = Kb + (size_t)(b * SS) * 2048 + h * 128;
    const __hip_bfloat16* Vtb = Vt + (size_t)(h * 128) * 4096 + b * SS;

    // Q B-frags (pre-scaled): qf[qs][ds], n = q = l15
    bf16x8 qf[2][4];
    #pragma unroll
    for (int qs = 0; qs < 2; qs++) {
        const __hip_bfloat16* qrow =
            Q + (size_t)(b * SS + qmin_w + qs * 16 + l15) * 2048 + h * 128;
        #pragma unroll
        for (int ds = 0; ds < 4; ds++)
            qf[qs][ds] = ld_frag(qrow + ds * 32 + quad * 8);
    }

    float m_i[2] = { -INFINITY, -INFINITY };
    float l_i[2] = { 0.0f, 0.0f };
    f32x4 acc[2][8] = {};

    const int Lr = lane >> 2;                      // 0..15 (row within issue)
    const int Lc = (lane & 3) ^ ((lane >> 3) & 3); // store-side chunk swizzle
    const int rsl = (l15 >> 1) & 3;                // read-side slot xor term
    const int kvh_w = w >> 1, dh_w = w & 1;        // V staging assignment
    const int ntiles = 2 * bxq + 2;

    for (int kt = 0; kt < ntiles; kt++) {
        const int kvbase = kt * 64;
        __syncthreads();   // all waves done reading prev tile's LDS

        // ---- stage K: wave w -> d-subtile w (4 issues x 1KB) ----
        #pragma unroll
        for (int i = 0; i < 4; i++) {
            GLD16(Kbase + (size_t)(kvbase + i * 16 + Lr) * 2048 + w * 32 + Lc * 8,
                  &Kt[w * 2048 + i * 512 + lane * 8]);
        }
        // ---- stage V: wave w -> kv-subtile w>>1, d-half w&1 ----
        #pragma unroll
        for (int i = 0; i < 4; i++) {
            GLD16(Vtb + (size_t)(dh_w * 64 + i * 16 + Lr) * 4096
                      + kvbase + kvh_w * 32 + Lc * 8,
                  &Vs[kvh_w * 4096 + dh_w * 2048 + i * 512 + lane * 8]);
        }
        __syncthreads();   // staged data visible

        // fully-masked for this wave? (stage-only participation)
        if (kvbase > qmax_w) continue;

        // ---- S^T = K * Q^T ----
        f32x4 st[4][2];
        #pragma unroll
        for (int kvsub = 0; kvsub < 4; kvsub++) {
            st[kvsub][0] = f32x4{};
            st[kvsub][1] = f32x4{};
            #pragma unroll
            for (int ds = 0; ds < 4; ds++) {
                bf16x8 kf = ld_frag(&Kt[ds * 2048 + (kvsub * 16 + l15) * 32
                                        + (quad ^ rsl) * 8]);
                #pragma unroll
                for (int qs = 0; qs < 2; qs++)
                    st[kvsub][qs] = __builtin_amdgcn_mfma_f32_16x16x32_bf16(
                        kf, qf[qs][ds], st[kvsub][qs], 0, 0, 0);
            }
        }
        // causal mask: only diagonal tiles need it (wave-uniform branch)
        if (kvbase + 63 > qmin_w) {
            #pragma unroll
            for (int qs = 0; qs < 2; qs++) {
                int q = qmin_w + qs * 16 + l15;
                #pragma unroll
                for (int kvsub = 0; kvsub < 4; kvsub++) {
                    #pragma unroll
                    for (int r = 0; r < 4; r++) {
                        int kv = kvbase + kvsub * 16 + quad * 4 + r;
                        if (kv > q) st[kvsub][qs][r] = -INFINITY;
                    }
                }
            }
        }

        // ---- online softmax (base 2) ----
        float alpha[2];
        bool anych = false;
        #pragma unroll
        for (int qs = 0; qs < 2; qs++) {
            float tm = st[0][qs][0];
            #pragma unroll
            for (int kvsub = 0; kvsub < 4; kvsub++)
                #pragma unroll
                for (int r = 0; r < 4; r++) tm = fmaxf(tm, st[kvsub][qs][r]);
            tm = fmaxf(tm, __shfl_xor(tm, 16));
            tm = fmaxf(tm, __shfl_xor(tm, 32));
            bool ch = __any(tm > m_i[qs]);
            float mnew = fmaxf(m_i[qs], tm);
            alpha[qs] = ch ? exp2f(m_i[qs] - mnew) : 1.0f;
            m_i[qs] = mnew;
            anych |= ch;
            float rs = 0.0f;
            #pragma unroll
            for (int kvsub = 0; kvsub < 4; kvsub++)
                #pragma unroll
                for (int r = 0; r < 4; r++) {
                    float pv = exp2f(st[kvsub][qs][r] - mnew);
                    st[kvsub][qs][r] = pv;
                    rs += pv;
                }
            rs += __shfl_xor(rs, 16);
            rs += __shfl_xor(rs, 32);
            l_i[qs] = l_i[qs] * alpha[qs] + rs;
        }

        // ---- write P to Sp (packed cvt, 4 kv per b64 store) ----
        #pragma unroll
        for (int qs = 0; qs < 2; qs++) {
            #pragma unroll
            for (int kvsub = 0; kvsub < 4; kvsub++) {
                uint2 pk = { pack_bf2(st[kvsub][qs][0], st[kvsub][qs][1]),
                             pack_bf2(st[kvsub][qs][2], st[kvsub][qs][3]) };
                *reinterpret_cast<uint2*>(
                    &Sp[w][(qs * 16 + l15) * 72 + kvsub * 16 + quad * 4]) = pk;
            }
        }

        // ---- rescale O accumulator (skipped when no max changed) ----
        if (anych) {
            #pragma unroll
            for (int qs = 0; qs < 2; qs++) {
                float al[4];
                #pragma unroll
                for (int r = 0; r < 4; r++) al[r] = __shfl(alpha[qs], quad * 4 + r, 64);
                #pragma unroll
                for (int dt = 0; dt < 8; dt++)
                    #pragma unroll
                    for (int r = 0; r < 4; r++) acc[qs][dt][r] *= al[r];
            }
        }

        // ---- PV: A = P (own wave's Sp), B = V (Vs) ----
        #pragma unroll
        for (int kvh = 0; kvh < 2; kvh++) {
            bf16x8 pf[2];
            #pragma unroll
            for (int qs = 0; qs < 2; qs++)
                pf[qs] = ld_frag(&Sp[w][(qs * 16 + l15) * 72 + kvh * 32 + quad * 8]);
            #pragma unroll
            for (int dt = 0; dt < 8; dt++) {
                bf16x8 vf = ld_frag(&Vs[kvh * 4096 + (dt * 16 + l15) * 32
                                        + (quad ^ rsl) * 8]);
                #pragma unroll
                for (int qs = 0; qs < 2; qs++)
                    acc[qs][dt] = __builtin_amdgcn_mfma_f32_16x16x32_bf16(
                        pf[qs], vf, acc[qs][dt], 0, 0, 0);
            }
        }
    }

    // ---- epilogue ----
    #pragma unroll
    for (int qs = 0; qs < 2; qs++) {
        float li[4];
        #pragma unroll
        for (int r = 0; r < 4; r++) li[r] = __shfl(l_i[qs], quad * 4 + r, 64);
        #pragma unroll
        for (int r = 0; r < 4; r++) {
            int row = qmin_w + qs * 16 + quad * 4 + r;
            __hip_bfloat16* orow = O + (size_t)(b * SS + row) * 2048 + h * 128;
            float inv_l = 1.0f / li[r];
            #pragma unroll
            for (int dt = 0; dt < 8; dt++)
                orow[dt * 16 + l15] = __float2bfloat16(acc[qs][dt][r] * inv_l);
        }
    }
}

// ---------------------------------------------------------------------------
extern "C" void kernel_launch(void* const* d_in, const int* in_sizes, int n_in,
                              void* d_out, int out_size, void* d_ws, size_t ws_size,
                              hipStream_t stream)
{
    const float* hs       = (const float*)d_in[0];
    const float* w_kv_d   = (const float*)d_in[1];
    const float* w_q_d    = (const float*)d_in[2];
    const float* w_k_u    = (const float*)d_in[3];
    const float* w_q_u    = (const float*)d_in[4];
    const float* w_v_u    = (const float*)d_in[5];
    const float* w_rope_k = (const float*)d_in[6];
    const float* w_rope_q = (const float*)d_in[7];
    const float* w_o      = (const float*)d_in[8];
    float* out = (float*)d_out;

    char* p = (char*)d_ws;
    auto alloc = [&](size_t nelem) {
        __hip_bfloat16* r = (__hip_bfloat16*)p;
        p += nelem * sizeof(__hip_bfloat16);
        return r;
    };
    __hip_bfloat16* hsb  = alloc((size_t)BS * HID);        // 16 MB (reused as attn)
    __hip_bfloat16* qkvd = alloc((size_t)BS * 512);        // 4 MB
    __hip_bfloat16* WT1  = alloc((size_t)1536 * 2048);     // 6 MB
    __hip_bfloat16* WT2  = alloc((size_t)3072 * 256);      // 1.5 MB
    __hip_bfloat16* WT3  = alloc((size_t)2048 * 256);      // 1 MB
    __hip_bfloat16* WTo  = alloc((size_t)2048 * 2048);     // 8 MB
    __hip_bfloat16* Kbuf = alloc((size_t)BS * HID);        // 16 MB
    __hip_bfloat16* Qbuf = alloc((size_t)BS * HID);        // 16 MB
    __hip_bfloat16* Vtb  = alloc((size_t)HID * BS);        // 16 MB, [h*128+d][b*S+s]
    __hip_bfloat16* attn = hsb;   // hs dead after G1

    dim3 blk(256);

    // 0a. hs -> bf16
    convert_kernel<<<dim3((BS * HID / 8 + 255) / 256), blk, 0, stream>>>(
        hs, hsb, BS * HID / 8);
    // 0b. all weights: transpose + convert to bf16 W^T
    transpose_weights_kernel<<<dim3(8448), blk, 0, stream>>>(
        w_kv_d, w_q_d, w_rope_k, w_k_u, w_v_u, w_q_u, w_rope_q, w_o,
        WT1, WT2, WT3, WTo);

    // G1: [kv_d | q_d | krp] = hsb @ WT1^T  (N=1536, K=2048)
    gemm_bt_kernel<__hip_bfloat16><<<dim3(1536 / 128, BS / 128), blk, 0, stream>>>(
        hsb, 2048, WT1,
        qkvd, 512, 0, 0, 1.0f,
        Kbuf, 2048, 1, 64, 1.0f,
        512, 2048);
    // G2: [k_p | v] = kv_d @ WT2^T  (N=3072, K=256)
    gemm_bt_kernel<__hip_bfloat16><<<dim3(3072 / 128, BS / 128), blk, 0, stream>>>(
        qkvd, 512, WT2,
        Kbuf, 2048, 1, 0, 1.0f,
        Vtb, 0, 2, 0, 1.0f,
        1024, 256);
    // G3: [q_p | q_rope_pre] = q_d @ WT3^T  (N=2048, K=256); Q pre-scaled
    gemm_bt_kernel<__hip_bfloat16><<<dim3(2048 / 128, BS / 128), blk, 0, stream>>>(
        qkvd + 256, 512, WT3,
        Qbuf, 2048, 1, 0, SCALE_L2E,
        Qbuf, 2048, 1, 64, SCALE_L2E,
        1024, 256);
    // 4. RoPE in-place on K/Q rope halves
    rope_kernel<<<dim3((BS * NH * 32 + 255) / 256), blk, 0, stream>>>(Kbuf, Qbuf);
    // 5. flash attention v6 -> attn
    flash_attn_kernel<<<dim3(SS / 128, NH, BB), blk, 0, stream>>>(
        Qbuf, Kbuf, Vtb, attn);
    // G4: out = attn @ WTo^T (fp32 out)
    gemm_bt_kernel<float><<<dim3(2048 / 128, BS / 128), blk, 0, stream>>>(
        attn, 2048, WTo,
        out, 2048, 0, 0, 1.0f,
        out, 2048, 0, 0, 1.0f,
        2048, 2048);
}

// Round 8
// 384.789 us; speedup vs baseline: 1.1748x; 1.1748x over previous
//
#include <hip/hip_runtime.h>
#include <hip/hip_bf16.h>

// Problem constants: B=2, S=2048, HID=2048, H=16, HD=128, HD2=64, LAT=256
#define BB 2
#define SS 2048
#define HID 2048
#define NH 16
#define BS (BB*SS)          // 4096 rows
#define SCALE 0.088388347648318447f   // 1/sqrt(128)

typedef __bf16 bf16x8 __attribute__((ext_vector_type(8)));
typedef float f32x4 __attribute__((ext_vector_type(4)));

__device__ __forceinline__ bf16x8 ld_frag(const __hip_bfloat16* p) {
    uint4 u = *reinterpret_cast<const uint4*>(p);
    return __builtin_bit_cast(bf16x8, u);
}
__device__ __forceinline__ void store_c(__hip_bfloat16* C, size_t idx, float v) {
    C[idx] = __float2bfloat16(v);
}
__device__ __forceinline__ void store_c(float* C, size_t idx, float v) {
    C[idx] = v;
}
__device__ __forceinline__ ushort bf_bits(float v) {
    __hip_bfloat16 h = __float2bfloat16(v);
    return *reinterpret_cast<ushort*>(&h);
}

// async global->LDS, 16B per lane; lds addr must be wave-uniform base + lane*16
#define GLD16(gp, lp) \
  __builtin_amdgcn_global_load_lds((const __attribute__((address_space(1))) void*)(gp), \
                                   (__attribute__((address_space(3))) void*)(lp), 16, 0, 0)

// ---------------------------------------------------------------------------
// fp32 -> bf16 flat convert (hs)
// ---------------------------------------------------------------------------
__global__ __launch_bounds__(256) void convert_kernel(
    const float* __restrict__ src, __hip_bfloat16* __restrict__ dst, int n8)
{
    int i = blockIdx.x * blockDim.x + threadIdx.x;
    if (i >= n8) return;
    float4 a = reinterpret_cast<const float4*>(src)[2 * i];
    float4 b = reinterpret_cast<const float4*>(src)[2 * i + 1];
    ushort u[8] = { bf_bits(a.x), bf_bits(a.y), bf_bits(a.z), bf_bits(a.w),
                    bf_bits(b.x), bf_bits(b.y), bf_bits(b.z), bf_bits(b.w) };
    reinterpret_cast<uint4*>(dst)[i] = *reinterpret_cast<uint4*>(u);
}

// ---------------------------------------------------------------------------
// Fused weight transpose+convert: 8 segments, src fp32 [R][C] -> dst bf16 [C][R]
// ---------------------------------------------------------------------------
__global__ __launch_bounds__(256) void transpose_weights_kernel(
    const float* s0, const float* s1, const float* s2, const float* s3,
    const float* s4, const float* s5, const float* s6, const float* s7,
    __hip_bfloat16* WT1, __hip_bfloat16* WT2, __hip_bfloat16* WT3,
    __hip_bfloat16* WTo)
{
    const float* srcs[8] = { s0, s1, s2, s3, s4, s5, s6, s7 };
    const int Rs[8] = { 2048, 2048, 2048, 256, 256, 256, 256, 2048 };
    const int Cs[8] = { 256, 256, 1024, 1024, 2048, 1024, 1024, 2048 };
    __hip_bfloat16* dsts[8] = {
        WT1, WT1 + (size_t)256 * 2048, WT1 + (size_t)512 * 2048,
        WT2, WT2 + (size_t)1024 * 256,
        WT3, WT3 + (size_t)1024 * 256,
        WTo };
    const int prefix[9] = { 0, 512, 1024, 3072, 3328, 3840, 4096, 4352, 8448 };

    int bid = blockIdx.x;
    int seg = 0;
    #pragma unroll
    for (int i = 0; i < 8; i++) if (bid >= prefix[i + 1]) seg = i + 1;
    int local = bid - prefix[seg];
    int R = Rs[seg], C = Cs[seg];
    int tilesC = C / 32;
    int tr = local / tilesC, tc = local % tilesC;
    int r0 = tr * 32, c0 = tc * 32;
    const float* src = srcs[seg];
    __hip_bfloat16* dst = dsts[seg];

    __shared__ float Ts[32][33];
    int t = threadIdx.x;
    int ty = t >> 5, tx = t & 31;
    #pragma unroll
    for (int k = 0; k < 4; k++) {
        int r = ty + k * 8;
        Ts[r][tx] = src[(size_t)(r0 + r) * C + c0 + tx];
    }
    __syncthreads();
    #pragma unroll
    for (int k = 0; k < 4; k++) {
        int r = ty + k * 8;
        dst[(size_t)(c0 + r) * R + r0 + tx] = __float2bfloat16(Ts[tx][r]);
    }
}

// ---------------------------------------------------------------------------
// m97-style GEMM: C = A[M,K] * Bt[N,K]^T, bf16 in, fp32 acc.
// 128x128 tile, BK=32, global_load_lds staging, 4 waves each 64x64.
// Epilogue routing: col < splitN -> (C0,...) else (C1,...). cm = output scale.
//   s64==0: plain col;  s64==1: col c -> (c>>6)*128 + (c&63) + off (head scatter)
//   s64==2: transposed store: Cp[(size_t)c*4096 + row]  (V-transpose for flash)
// ---------------------------------------------------------------------------
template <typename TC>
__global__ __launch_bounds__(256) void gemm_bt_kernel(
    const __hip_bfloat16* __restrict__ A, int lda,
    const __hip_bfloat16* __restrict__ Bt,
    TC* __restrict__ C0, int ldc0, int sp0, int off0, float cm0,
    TC* __restrict__ C1, int ldc1, int sp1, int off1, float cm1,
    int splitN, int K)
{
    __shared__ alignas(16) __hip_bfloat16 As[128 * 32];
    __shared__ alignas(16) __hip_bfloat16 Bs[128 * 32];

    const int bn = blockIdx.x * 128;
    const int bm = blockIdx.y * 128;
    const int t = threadIdx.x;
    const int w = t >> 6;
    const int lane = t & 63;
    const int l15 = lane & 15;
    const int quad = lane >> 4;
    const int wm = (w & 1) * 64;
    const int wn = (w >> 1) * 64;

    const int srow = lane >> 2;          // 0..15
    const int skcol = (lane & 3) * 8;    // 0,8,16,24

    f32x4 acc[4][4] = {};

    for (int k0 = 0; k0 < K; k0 += 32) {
        __syncthreads();
        #pragma unroll
        for (int i = 0; i < 2; i++) {
            int r = w * 32 + i * 16 + srow;
            GLD16(A + (size_t)(bm + r) * lda + k0 + skcol, &As[r * 32 + skcol]);
            GLD16(Bt + (size_t)(bn + r) * K + k0 + skcol, &Bs[r * 32 + skcol]);
        }
        __syncthreads();

        bf16x8 af[4], bf[4];
        #pragma unroll
        for (int mt = 0; mt < 4; mt++)
            af[mt] = ld_frag(&As[(wm + mt * 16 + l15) * 32 + quad * 8]);
        #pragma unroll
        for (int nt = 0; nt < 4; nt++)
            bf[nt] = ld_frag(&Bs[(wn + nt * 16 + l15) * 32 + quad * 8]);
        #pragma unroll
        for (int mt = 0; mt < 4; mt++)
            #pragma unroll
            for (int nt = 0; nt < 4; nt++)
                acc[mt][nt] = __builtin_amdgcn_mfma_f32_16x16x32_bf16(
                    af[mt], bf[nt], acc[mt][nt], 0, 0, 0);
    }

    #pragma unroll
    for (int nt = 0; nt < 4; nt++) {
        int col = bn + wn + nt * 16 + l15;
        TC* Cp; int c, ld, s64, off; float cm;
        if (col < splitN) { Cp = C0; c = col; ld = ldc0; s64 = sp0; off = off0; cm = cm0; }
        else { Cp = C1; c = col - splitN; ld = ldc1; s64 = sp1; off = off1; cm = cm1; }
        if (s64 == 2) {
            #pragma unroll
            for (int mt = 0; mt < 4; mt++) {
                int row0 = bm + wm + mt * 16 + quad * 4;
                #pragma unroll
                for (int r = 0; r < 4; r++)
                    store_c(Cp, (size_t)c * 4096 + row0 + r, acc[mt][nt][r] * cm);
            }
        } else {
            int oc = s64 ? ((c >> 6) * 128 + (c & 63) + off) : c;
            #pragma unroll
            for (int mt = 0; mt < 4; mt++) {
                #pragma unroll
                for (int r = 0; r < 4; r++) {
                    int row = bm + wm + mt * 16 + quad * 4 + r;
                    store_c(Cp, (size_t)row * ld + oc, acc[mt][nt][r] * cm);
                }
            }
        }
    }
}

// ---------------------------------------------------------------------------
// RoPE in-place on K/Q rope halves: cols h*128+64+i and h*128+96+i rotated.
// ---------------------------------------------------------------------------
__global__ __launch_bounds__(256) void rope_kernel(
    __hip_bfloat16* __restrict__ Kb, __hip_bfloat16* __restrict__ Qb)
{
    int idx = blockIdx.x * blockDim.x + threadIdx.x;
    if (idx >= BS * NH * 32) return;
    int i = idx & 31;
    int h = (idx >> 5) & 15;
    int row = idx >> 9;
    int s = row & (SS - 1);

    float inv = exp2f(-(float)i * 0.4152410118609203f);  // 10000^(-i/32)
    float ang = (float)s * inv;
    float sn = sinf(ang), cs = cosf(ang);

    size_t obase = (size_t)row * 2048 + h * 128 + 64 + i;
    {
        float x1 = __bfloat162float(Kb[obase]);
        float x2 = __bfloat162float(Kb[obase + 32]);
        Kb[obase]      = __float2bfloat16(x1 * cs - x2 * sn);
        Kb[obase + 32] = __float2bfloat16(x1 * sn + x2 * cs);
    }
    {
        float x1 = __bfloat162float(Qb[obase]);
        float x2 = __bfloat162float(Qb[obase + 32]);
        Qb[obase]      = __float2bfloat16(x1 * cs - x2 * sn);
        Qb[obase + 32] = __float2bfloat16(x1 * sn + x2 * cs);
    }
}

// ---------------------------------------------------------------------------
// Flash attention v7 = v4 (131 us, branchless body) + ONE change: the
// verified conflict-free LDS chunk swizzle (r7 counter evidence:
// SQ_LDS_BANK_CONFLICT 5.9M -> 1.6M). Store chunk (lane&3)^((lane>>3)&3),
// read slot quad^((l15>>1)&3). No wave-level branches in the K-loop body:
// every tile runs mask+softmax+PV straight-line (the v5/v6 branchy variants
// regressed 131 -> 165/194 us despite "less work").
// ---------------------------------------------------------------------------
__global__ __launch_bounds__(256) void flash_attn_kernel(
    const __hip_bfloat16* __restrict__ Q,
    const __hip_bfloat16* __restrict__ Kb,
    const __hip_bfloat16* __restrict__ Vt,
    __hip_bfloat16* __restrict__ O)
{
    __shared__ alignas(16) __hip_bfloat16 Kt[4 * 64 * 32];   // subtile ds: [64 kv][32 d]
    __shared__ alignas(16) __hip_bfloat16 Vs[2 * 128 * 32];  // subtile kvh: [128 d][32 kv]
    __shared__ alignas(16) __hip_bfloat16 Sp[4][32 * 72];    // per-wave P [32 q][72]

    const int bxq = (gridDim.x - 1) - blockIdx.x;   // big blocks dispatched first
    const int h = blockIdx.y;
    const int b = blockIdx.z;
    const int t = threadIdx.x;
    const int w = t >> 6;
    const int lane = t & 63;
    const int l15 = lane & 15;
    const int quad = lane >> 4;
    const int qbase = bxq * 128;

    const __hip_bfloat16* Kbase = Kb + (size_t)(b * SS) * 2048 + h * 128;
    const __hip_bfloat16* Vtb = Vt + (size_t)(h * 128) * 4096 + b * SS;

    // Q B-frags: qf[qs][ds], n = q = l15
    bf16x8 qf[2][4];
    #pragma unroll
    for (int qs = 0; qs < 2; qs++) {
        const __hip_bfloat16* qrow =
            Q + (size_t)(b * SS + qbase + w * 32 + qs * 16 + l15) * 2048 + h * 128;
        #pragma unroll
        for (int ds = 0; ds < 4; ds++)
            qf[qs][ds] = ld_frag(qrow + ds * 32 + quad * 8);
    }

    float m_i[2] = { -INFINITY, -INFINITY };
    float l_i[2] = { 0.0f, 0.0f };
    f32x4 acc[2][8] = {};

    const int Lr = lane >> 2;                      // 0..15 (row within issue)
    const int Lc = (lane & 3) ^ ((lane >> 3) & 3); // store-side chunk swizzle
    const int rsl = (l15 >> 1) & 3;                // read-side slot xor term
    const int kvh_w = w >> 1, dh_w = w & 1;        // V staging assignment
    const int ntiles = 2 * bxq + 2;

    for (int kt = 0; kt < ntiles; kt++) {
        const int kvbase = kt * 64;
        __syncthreads();   // all waves done reading prev tile's LDS

        // ---- stage K: wave w -> d-subtile w (4 issues x 1KB) ----
        #pragma unroll
        for (int i = 0; i < 4; i++) {
            GLD16(Kbase + (size_t)(kvbase + i * 16 + Lr) * 2048 + w * 32 + Lc * 8,
                  &Kt[w * 2048 + i * 512 + lane * 8]);
        }
        // ---- stage V: wave w -> kv-subtile w>>1, d-half w&1 ----
        #pragma unroll
        for (int i = 0; i < 4; i++) {
            GLD16(Vtb + (size_t)(dh_w * 64 + i * 16 + Lr) * 4096
                      + kvbase + kvh_w * 32 + Lc * 8,
                  &Vs[kvh_w * 4096 + dh_w * 2048 + i * 512 + lane * 8]);
        }
        __syncthreads();   // staged data visible

        // ---- S^T = K * Q^T ----
        f32x4 st[4][2];
        #pragma unroll
        for (int kvsub = 0; kvsub < 4; kvsub++) {
            st[kvsub][0] = f32x4{};
            st[kvsub][1] = f32x4{};
            #pragma unroll
            for (int ds = 0; ds < 4; ds++) {
                bf16x8 kf = ld_frag(&Kt[ds * 2048 + (kvsub * 16 + l15) * 32
                                        + (quad ^ rsl) * 8]);
                #pragma unroll
                for (int qs = 0; qs < 2; qs++)
                    st[kvsub][qs] = __builtin_amdgcn_mfma_f32_16x16x32_bf16(
                        kf, qf[qs][ds], st[kvsub][qs], 0, 0, 0);
            }
        }
        // scale + causal mask (every tile, branchless)
        #pragma unroll
        for (int qs = 0; qs < 2; qs++) {
            int q = qbase + w * 32 + qs * 16 + l15;
            #pragma unroll
            for (int kvsub = 0; kvsub < 4; kvsub++) {
                #pragma unroll
                for (int r = 0; r < 4; r++) {
                    int kv = kvbase + kvsub * 16 + quad * 4 + r;
                    st[kvsub][qs][r] = (kv <= q) ? st[kvsub][qs][r] * SCALE
                                                 : -INFINITY;
                }
            }
        }

        // ---- online softmax per qsub (q = l15, in-lane 16 + 2 shuffles) ----
        float alpha[2];
        #pragma unroll
        for (int qs = 0; qs < 2; qs++) {
            float tm = st[0][qs][0];
            #pragma unroll
            for (int kvsub = 0; kvsub < 4; kvsub++)
                #pragma unroll
                for (int r = 0; r < 4; r++) tm = fmaxf(tm, st[kvsub][qs][r]);
            tm = fmaxf(tm, __shfl_xor(tm, 16));
            tm = fmaxf(tm, __shfl_xor(tm, 32));
            float mnew = fmaxf(m_i[qs], tm);
            float rs = 0.0f;
            #pragma unroll
            for (int kvsub = 0; kvsub < 4; kvsub++)
                #pragma unroll
                for (int r = 0; r < 4; r++) {
                    float pv = __expf(st[kvsub][qs][r] - mnew);
                    st[kvsub][qs][r] = pv;
                    rs += pv;
                }
            rs += __shfl_xor(rs, 16);
            rs += __shfl_xor(rs, 32);
            alpha[qs] = __expf(m_i[qs] - mnew);
            m_i[qs] = mnew;
            l_i[qs] = l_i[qs] * alpha[qs] + rs;
        }

        // ---- write P to Sp (4 consecutive kv per b64 store) ----
        #pragma unroll
        for (int qs = 0; qs < 2; qs++) {
            #pragma unroll
            for (int kvsub = 0; kvsub < 4; kvsub++) {
                ushort pk[4] = { bf_bits(st[kvsub][qs][0]), bf_bits(st[kvsub][qs][1]),
                                 bf_bits(st[kvsub][qs][2]), bf_bits(st[kvsub][qs][3]) };
                *reinterpret_cast<uint2*>(
                    &Sp[w][(qs * 16 + l15) * 72 + kvsub * 16 + quad * 4]) =
                    *reinterpret_cast<uint2*>(pk);
            }
        }

        // ---- rescale O accumulator ----
        #pragma unroll
        for (int qs = 0; qs < 2; qs++) {
            float al[4];
            #pragma unroll
            for (int r = 0; r < 4; r++) al[r] = __shfl(alpha[qs], quad * 4 + r, 64);
            #pragma unroll
            for (int dt = 0; dt < 8; dt++)
                #pragma unroll
                for (int r = 0; r < 4; r++) acc[qs][dt][r] *= al[r];
        }

        // ---- PV: A = P (own wave's Sp), B = V (Vs) ----
        #pragma unroll
        for (int kvh = 0; kvh < 2; kvh++) {
            bf16x8 pf[2];
            #pragma unroll
            for (int qs = 0; qs < 2; qs++)
                pf[qs] = ld_frag(&Sp[w][(qs * 16 + l15) * 72 + kvh * 32 + quad * 8]);
            #pragma unroll
            for (int dt = 0; dt < 8; dt++) {
                bf16x8 vf = ld_frag(&Vs[kvh * 4096 + (dt * 16 + l15) * 32
                                        + (quad ^ rsl) * 8]);
                #pragma unroll
                for (int qs = 0; qs < 2; qs++)
                    acc[qs][dt] = __builtin_amdgcn_mfma_f32_16x16x32_bf16(
                        pf[qs], vf, acc[qs][dt], 0, 0, 0);
            }
        }
    }

    // ---- epilogue ----
    #pragma unroll
    for (int qs = 0; qs < 2; qs++) {
        float li[4];
        #pragma unroll
        for (int r = 0; r < 4; r++) li[r] = __shfl(l_i[qs], quad * 4 + r, 64);
        #pragma unroll
        for (int r = 0; r < 4; r++) {
            int row = qbase + w * 32 + qs * 16 + quad * 4 + r;
            __hip_bfloat16* orow = O + (size_t)(b * SS + row) * 2048 + h * 128;
            float inv_l = 1.0f / li[r];
            #pragma unroll
            for (int dt = 0; dt < 8; dt++)
                orow[dt * 16 + l15] = __float2bfloat16(acc[qs][dt][r] * inv_l);
        }
    }
}

// ---------------------------------------------------------------------------
extern "C" void kernel_launch(void* const* d_in, const int* in_sizes, int n_in,
                              void* d_out, int out_size, void* d_ws, size_t ws_size,
                              hipStream_t stream)
{
    const float* hs       = (const float*)d_in[0];
    const float* w_kv_d   = (const float*)d_in[1];
    const float* w_q_d    = (const float*)d_in[2];
    const float* w_k_u    = (const float*)d_in[3];
    const float* w_q_u    = (const float*)d_in[4];
    const float* w_v_u    = (const float*)d_in[5];
    const float* w_rope_k = (const float*)d_in[6];
    const float* w_rope_q = (const float*)d_in[7];
    const float* w_o      = (const float*)d_in[8];
    float* out = (float*)d_out;

    char* p = (char*)d_ws;
    auto alloc = [&](size_t nelem) {
        __hip_bfloat16* r = (__hip_bfloat16*)p;
        p += nelem * sizeof(__hip_bfloat16);
        return r;
    };
    __hip_bfloat16* hsb  = alloc((size_t)BS * HID);        // 16 MB (reused as attn)
    __hip_bfloat16* qkvd = alloc((size_t)BS * 512);        // 4 MB
    __hip_bfloat16* WT1  = alloc((size_t)1536 * 2048);     // 6 MB
    __hip_bfloat16* WT2  = alloc((size_t)3072 * 256);      // 1.5 MB
    __hip_bfloat16* WT3  = alloc((size_t)2048 * 256);      // 1 MB
    __hip_bfloat16* WTo  = alloc((size_t)2048 * 2048);     // 8 MB
    __hip_bfloat16* Kbuf = alloc((size_t)BS * HID);        // 16 MB
    __hip_bfloat16* Qbuf = alloc((size_t)BS * HID);        // 16 MB
    __hip_bfloat16* Vtb  = alloc((size_t)HID * BS);        // 16 MB, [h*128+d][b*S+s]
    __hip_bfloat16* attn = hsb;   // hs dead after G1

    dim3 blk(256);

    // 0a. hs -> bf16
    convert_kernel<<<dim3((BS * HID / 8 + 255) / 256), blk, 0, stream>>>(
        hs, hsb, BS * HID / 8);
    // 0b. all weights: transpose + convert to bf16 W^T
    transpose_weights_kernel<<<dim3(8448), blk, 0, stream>>>(
        w_kv_d, w_q_d, w_rope_k, w_k_u, w_v_u, w_q_u, w_rope_q, w_o,
        WT1, WT2, WT3, WTo);

    // G1: [kv_d | q_d | krp] = hsb @ WT1^T  (N=1536, K=2048)
    gemm_bt_kernel<__hip_bfloat16><<<dim3(1536 / 128, BS / 128), blk, 0, stream>>>(
        hsb, 2048, WT1,
        qkvd, 512, 0, 0, 1.0f,
        Kbuf, 2048, 1, 64, 1.0f,
        512, 2048);
    // G2: [k_p | v] = kv_d @ WT2^T  (N=3072, K=256)
    gemm_bt_kernel<__hip_bfloat16><<<dim3(3072 / 128, BS / 128), blk, 0, stream>>>(
        qkvd, 512, WT2,
        Kbuf, 2048, 1, 0, 1.0f,
        Vtb, 0, 2, 0, 1.0f,
        1024, 256);
    // G3: [q_p | q_rope_pre] = q_d @ WT3^T  (N=2048, K=256)
    gemm_bt_kernel<__hip_bfloat16><<<dim3(2048 / 128, BS / 128), blk, 0, stream>>>(
        qkvd + 256, 512, WT3,
        Qbuf, 2048, 1, 0, 1.0f,
        Qbuf, 2048, 1, 64, 1.0f,
        1024, 256);
    // 4. RoPE in-place on K/Q rope halves
    rope_kernel<<<dim3((BS * NH * 32 + 255) / 256), blk, 0, stream>>>(Kbuf, Qbuf);
    // 5. flash attention v7 -> attn
    flash_attn_kernel<<<dim3(SS / 128, NH, BB), blk, 0, stream>>>(
        Qbuf, Kbuf, Vtb, attn);
    // G4: out = attn @ WTo^T (fp32 out)
    gemm_bt_kernel<float><<<dim3(2048 / 128, BS / 128), blk, 0, stream>>>(
        attn, 2048, WTo,
        out, 2048, 0, 0, 1.0f,
        out, 2048, 0, 0, 1.0f,
        2048, 2048);
}